// Round 12
// baseline (183.086 us; speedup 1.0000x reference)
//
#include <hip/hip_runtime.h>
#include <cmath>
#include <cstdint>
#include <cstring>

// Problem constants (B,C,H,W) = (16,3,512,512), window 11, patch 16.
#define OUTD 502          // 512 - 11 + 1
#define TSX  64           // output tile width
#define TSY  16           // output tile height (back to 16: register-cliff test)
#define HT2P   20         // transpose buffer row pitch (f16): 40 B
#define NTAP 11
#define GX   8            // ceil(502/64)
#define GY   32           // ceil(502/16)
#define NPARTIAL (48 * GY * GX)   // 12288

typedef float    f32x4 __attribute__((ext_vector_type(4)));
typedef _Float16 f16x4 __attribute__((ext_vector_type(4)));
typedef _Float16 f16x8 __attribute__((ext_vector_type(8)));
typedef __attribute__((address_space(3))) const _Float16 lds_cf16;

struct GW { float g[NTAP]; float cm; };  // g: fp16-rounded weights; cm = 1/(sum g)^2

__device__ __forceinline__ f32x4 mfma_f16(f16x8 a, f16x8 b, f32x4 c) {
    return __builtin_amdgcn_mfma_f32_16x16x32_f16(a, b, c, 0, 0, 0);
}

// Kernel 1: per-patch (16x16) max of the int mask -> small[b][32][32]
__global__ __launch_bounds__(256) void patch_max_kernel(const int* __restrict__ mask,
                                                        int* __restrict__ smallbuf) {
    const int py = blockIdx.x;   // 0..31 patch row
    const int b  = blockIdx.y;   // 0..15 image
    const int tid = threadIdx.x;
    const int lane = tid & 63, wv = tid >> 6;
    const int4* m4 = (const int4*)(mask + ((size_t)b << 18) + (size_t)py * 16 * 512);
    #pragma unroll
    for (int j = 0; j < 8; ++j) {
        int px  = wv + 4 * j;
        int row = lane >> 2, q = lane & 3;
        int4 v = m4[row * 128 + px * 4 + q];
        int mx = max(max(v.x, v.y), max(v.z, v.w));
        #pragma unroll
        for (int off = 32; off >= 1; off >>= 1) mx = max(mx, __shfl_xor(mx, off));
        if (lane == 0) smallbuf[((b << 5) + py) * 32 + px] = mx;
    }
}

// Kernel 2: MFMA separable-Gaussian SSIM over a 64x16 output tile.
// R12 revision -- OCCUPANCY-CLIFF TEST, the safe construction. R10's forced
// __launch_bounds__(256,8) two-pass variant produced NaN (suspected
// regalloc/spill interaction with inline asm under forced 64-reg pressure;
// bundle abandoned, not debugged). The theory stands untested: R6/R9's
// structurally different TSY=32 bodies all sit at 62.5 us / 44% occupancy
// (48 arch + 32 acc = 80 regs -> 4 waves/SIMD bin), issue only ~16% of wall
// time -> wave-starved. This kernel shrinks the tile to TSY=16 so the
// accumulator is ONE f32x4[4] (16 regs) and natural pressure is ~48 regs
// (R3 measured 48 -> 79% occupancy) -- no forcing, no acc reuse. Body is
// the PROVEN R6 per-map sequence (2 H-MFMA -> 2 ds_write_b64 -> 2 hw
// tr-reads -> lgkmcnt(0) -> V-MFMA), which passed absmax 0.0 in R5/R6/R9.
// Cost: ~25-30% more issue work per output (halo, per-tile overhead) --
// cheap if issue is as idle as measured. Benefit: ~2x resident waves.
__global__ __launch_bounds__(256) void ssim_kernel(const float* __restrict__ img1,
                                                   const float* __restrict__ img2,
                                                   const int* __restrict__ smallbuf,
                                                   float* __restrict__ partial, GW gw) {
    __shared__ __align__(16) _Float16 sHT[4][32][HT2P];   // 5120 B per-wave H-results
    __shared__ _Float16 gpad[48];               // zero-padded taps: gpad[15+i]=g[i]
    __shared__ int sdil[10];                    // 2 patch-rows x 5 patch-cols
    __shared__ float wsum[4];

    const int tid  = threadIdx.x;
    const int wv   = tid >> 6, lane = tid & 63;
    const int nidx = lane & 15, quad = lane >> 4;
    const int x0 = blockIdx.x * TSX, y0 = blockIdx.y * TSY;
    const int bc = blockIdx.z;               // b*3 + c
    const size_t base = (size_t)bc << 18;    // *512*512

    // This wave handles output cols cb..cb+15 of the tile.
    const int cb = 16 * wv;

    // Direct global->reg B-frags: lane (quad,nidx) covers row y0+16h+nidx
    // (h=0,1), cols gxc..gxc+7. Clamps: col base <=504, row <=511. Clamped
    // or beyond-window rows (k=26..31) only meet zero taps (g[k-m]=0 for
    // k-m>10 at all valid outputs) or discarded outputs; data is finite.
    int gxc = x0 + cb + quad * 8; gxc = gxc > 504 ? 504 : gxc;
    f16x8 fa[2], fb[2];
    #pragma unroll
    for (int h = 0; h < 2; ++h) {
        int gy = y0 + 16 * h + nidx; gy = gy > 511 ? 511 : gy;
        const float* p1 = img1 + base + ((size_t)gy << 9) + gxc;
        const float* p2 = img2 + base + ((size_t)gy << 9) + gxc;
        f32x4 alo = *(const f32x4*)p1, ahi = *(const f32x4*)(p1 + 4);
        f32x4 blo = *(const f32x4*)p2, bhi = *(const f32x4*)(p2 + 4);
        f16x4 al = __builtin_convertvector(alo, f16x4);
        f16x4 ah = __builtin_convertvector(ahi, f16x4);
        f16x4 bl = __builtin_convertvector(blo, f16x4);
        f16x4 bh = __builtin_convertvector(bhi, f16x4);
        fa[h] = __builtin_shufflevector(al, ah, 0, 1, 2, 3, 4, 5, 6, 7);
        fb[h] = __builtin_shufflevector(bl, bh, 0, 1, 2, 3, 4, 5, 6, 7);
    }

    // padded tap table (indices 15..25 hold g[0..10], rest zero)
    if (tid < 48) {
        int k = tid - 15;
        int kc = k < 0 ? 0 : (k > 10 ? 10 : k);      // clamp: no speculative OOB
        gpad[tid] = (k == kc) ? (_Float16)gw.g[kc] : (_Float16)0.f;
    }

    // fused 3x3 dilation lookup: tile spans patch rows by..by+1 (window
    // reaches y0+25), patch cols bx*4 .. bx*4+4.
    if (tid >= 192 && tid < 202) {
        int t = tid - 192;
        int pr = (int)blockIdx.y + (t >= 5 ? 1 : 0);
        int pc = (int)blockIdx.x * 4 + (t >= 5 ? t - 5 : t);
        int acc = 0;
        if (pr < 32 && pc < 32) {
            const int* sb = smallbuf + ((bc / 3) << 10);
            #pragma unroll
            for (int dy = -1; dy <= 1; ++dy)
                #pragma unroll
                for (int dx = -1; dx <= 1; ++dx) {
                    int ny = pr + dy, nx = pc + dx;
                    if (ny >= 0 && ny < 32 && nx >= 0 && nx < 32) acc |= sb[(ny << 5) + nx];
                }
        }
        sdil[t] = acc ? 1 : 0;
    }
    __syncthreads();

    // Toeplitz A-frag (shared by both passes): A[m=nidx][k=quad*8+j] = g[k-m].
    f16x8 af;
    {
        const _Float16* gp = &gpad[quad * 8 - nidx + 15];
        #pragma unroll
        for (int j = 0; j < 8; ++j) af[j] = gp[j];
    }

    // Transpose-buffer addresses (per-wave region sHT[wv], 40 B rows):
    // write: lane(quad,nidx) holds (x' = 4*quad+r, y = 16h+nidx) -> word at
    //        row 16h+nidx, col 4*quad (one b64 per h; +320 f16 for h=1).
    _Float16* wp = &sHT[wv][nidx][quad * 4];
    // tr read: lane(q,m) fetches word (y = 8q + (m>>2) [+4], w = m&3).
    lds_cf16* rp = (lds_cf16*)&sHT[wv][8 * quad + (nidx >> 2)][4 * (nidx & 3)];

    // Per map: 2 H-MFMAs -> row-major sHT -> 2 tr-reads -> 1 V-MFMA.
    // Same in-order-DS sequence as R6 (absmax 0.0 verified).
    f32x4 acc[4];
    #pragma unroll
    for (int mm = 0; mm < 4; ++mm) {
        f16x8 f0, f1;
        if (mm == 0)      { f0 = fa[0]; f1 = fa[1]; }
        else if (mm == 1) { f0 = fb[0]; f1 = fb[1]; }
        else if (mm == 2) { f0 = fa[0] * fb[0]; f1 = fa[1] * fb[1]; }
        else              { f0 = fa[0] * fa[0] + fb[0] * fb[0];
                            f1 = fa[1] * fa[1] + fb[1] * fb[1]; }
        f32x4 z = {0.f, 0.f, 0.f, 0.f};
        f32x4 c0 = mfma_f16(af, f0, z);   // H-conv rows 0..15
        f32x4 c1 = mfma_f16(af, f1, z);   // rows 16..31
        // C layout: x' = quad*4+r (consecutive r!), y = data row = nidx + 16h
        *(f16x4*)(wp)       = __builtin_convertvector(c0, f16x4);
        *(f16x4*)(wp + 320) = __builtin_convertvector(c1, f16x4);
        // V-pass B-frag via HW transpose read: k rows 0..31 ->
        // offsets 0 (rows 8q+0..3) and 160 (+4 rows).
        f16x4 r0, r1;
        asm volatile("ds_read_b64_tr_b16 %0, %2 offset:0\n\t"
                     "ds_read_b64_tr_b16 %1, %2 offset:160"
                     : "=&v"(r0), "=&v"(r1)
                     : "v"(rp) : "memory");
        asm volatile("s_waitcnt lgkmcnt(0)" ::: "memory");
        __builtin_amdgcn_sched_barrier(0);   // rule #18: keep MFMA after the wait
        f16x8 hb = __builtin_shufflevector(r0, r1, 0, 1, 2, 3, 4, 5, 6, 7);
        acc[mm] = mfma_f16(af, hb, z);
    }

    // Epilogue: lane holds 4 maps x 4 pixels at y = y0+quad*4+r, x = x0+cb+nidx
    const float C1v = 1e-4f, C2v = 9e-4f;  // L = 1 (inputs uniform [0,1))
    const float cm = gw.cm;
    float lsum = 0.f;
    {
        const int xl = cb + nidx;
        const int x = x0 + xl;
        if (x < OUTD) {
            const int lc0 = xl >> 4, lc1 = (xl + 10) >> 4;
            const int vm0 = sdil[lc0] & sdil[lc1];
            const int vm1 = vm0 & sdil[5 + lc0] & sdil[5 + lc1];
            #pragma unroll
            for (int r = 0; r < 4; ++r) {
                int q4r = quad * 4 + r;
                int y = y0 + q4r;
                if (y < OUTD) {
                    // lr1 = (q4r+10)>>4 is 1 iff q4r >= 6
                    int validm = (q4r >= 6) ? vm1 : vm0;
                    float mu1 = acc[0][r] * cm, mu2 = acc[1][r] * cm;
                    float Sab = acc[2][r] * cm, Sss = acc[3][r] * cm;
                    float mu1s = mu1 * mu1, mu2s = mu2 * mu2, mu12 = mu1 * mu2;
                    float sg12 = Sab - mu12;
                    float sigS = Sss - mu1s - mu2s;
                    float num = (2.f * mu12 + C1v) * (2.f * sg12 + C2v);
                    float den = (mu1s + mu2s + C1v) * (sigS + C2v);
                    if (validm) lsum += __fdividef(num, den);
                }
            }
        }
    }

    // block reduction -> one float partial per block (deterministic, no atomics)
    #pragma unroll
    for (int off = 32; off >= 1; off >>= 1) lsum += __shfl_xor(lsum, off);
    if ((tid & 63) == 0) wsum[tid >> 6] = lsum;
    __syncthreads();
    if (tid == 0)
        partial[((int)blockIdx.z * GY + (int)blockIdx.y) * GX + (int)blockIdx.x] =
            wsum[0] + wsum[1] + wsum[2] + wsum[3];
}

// Kernel 3: reduce partials, divide by element count (deterministic order)
__global__ __launch_bounds__(256) void finalize_kernel(const float* __restrict__ partial,
                                                       float* __restrict__ out) {
    __shared__ double sd[256];
    double s = 0.0;
    const f32x4* p4 = (const f32x4*)partial;
    for (int i = threadIdx.x; i < NPARTIAL / 4; i += 256) {
        f32x4 vv = p4[i];
        s += (double)vv.x + (double)vv.y + (double)vv.z + (double)vv.w;
    }
    sd[threadIdx.x] = s;
    __syncthreads();
    for (int st = 128; st >= 1; st >>= 1) {
        if (threadIdx.x < st) sd[threadIdx.x] += sd[threadIdx.x + st];
        __syncthreads();
    }
    if (threadIdx.x == 0) out[0] = (float)(sd[0] / 12096192.0);  // 16*3*502*502
}

// Round a positive normal double to the nearest fp16-representable float (RTNE).
static inline float fp16_rtne(double x) {
    float f = (float)x;
    uint32_t u; memcpy(&u, &f, 4);
    // drop 13 mantissa bits (23 -> 10), RTNE with carry into exponent
    u = (u + 0xFFFu + ((u >> 13) & 1u)) & ~0x1FFFu;
    memcpy(&f, &u, 4);
    return f;
}

extern "C" void kernel_launch(void* const* d_in, const int* in_sizes, int n_in,
                              void* d_out, int out_size, void* d_ws, size_t ws_size,
                              hipStream_t stream) {
    const float* img1 = (const float*)d_in[0];
    const float* img2 = (const float*)d_in[1];
    const int*   mask = (const int*)d_in[2];
    float* out = (float*)d_out;

    char* ws = (char*)d_ws;
    float* partial  = (float*)ws;                        // 12288 floats
    int*   smallbuf = (int*)(ws + NPARTIAL * 4);         // 16*32*32 ints

    // Gaussian(sigma=1.5), normalized in double, then each tap rounded to
    // fp16 (RTNE). cm = 1/(sum of rounded taps)^2 removes the systematic
    // scale error of fp16 conv weights (applied to all 4 maps in epilogue).
    GW gw;
    double gd[NTAP], gsum = 0.0;
    for (int i = 0; i < NTAP; ++i) {
        double x = (double)(i - 5);
        gd[i] = exp(-(x * x) / 4.5);
        gsum += gd[i];
    }
    double wsumr = 0.0;
    for (int i = 0; i < NTAP; ++i) {
        gw.g[i] = fp16_rtne(gd[i] / gsum);
        wsumr += (double)gw.g[i];
    }
    gw.cm = (float)(1.0 / (wsumr * wsumr));

    patch_max_kernel<<<dim3(32, 16), 256, 0, stream>>>(mask, smallbuf);
    ssim_kernel<<<dim3(GX, GY, 48), 256, 0, stream>>>(img1, img2, smallbuf, partial, gw);
    finalize_kernel<<<1, 256, 0, stream>>>(partial, out);
}

// Round 13
// 171.173 us; speedup vs baseline: 1.0696x; 1.0696x over previous
//
#include <hip/hip_runtime.h>
#include <cmath>
#include <cstdint>
#include <cstring>

// Problem constants (B,C,H,W) = (16,3,512,512), window 11, patch 16.
#define OUTD 502          // 512 - 11 + 1
#define TSX  64           // output tile width
#define TSY  48           // output tile height (3 groups of 16)
#define SPITCH 88         // staged row pitch (f16): 176 B, 16B-mult
#define SROWS  64         // 58 data rows + 6 zero pad (B-frag k reaches 63)
#define HT2P   20         // transpose buffer row pitch (f16): 40 B
#define NTAP 11
#define GX   8            // ceil(502/64)
#define GY   11           // ceil(502/48)
#define NPARTIAL (48 * GY * GX)   // 4224

typedef float    f32x2 __attribute__((ext_vector_type(2)));
typedef float    f32x4 __attribute__((ext_vector_type(4)));
typedef _Float16 f16x4 __attribute__((ext_vector_type(4)));
typedef _Float16 f16x8 __attribute__((ext_vector_type(8)));
typedef __attribute__((address_space(3))) const _Float16 lds_cf16;

struct GW { float g[NTAP]; float cm; };  // g: fp16-rounded weights; cm = 1/(sum g)^2

__device__ __forceinline__ f32x4 mfma_f16(f16x8 a, f16x8 b, f32x4 c) {
    return __builtin_amdgcn_mfma_f32_16x16x32_f16(a, b, c, 0, 0, 0);
}

// Kernel 1: per-patch (16x16) max of the int mask -> small[b][32][32]
__global__ __launch_bounds__(256) void patch_max_kernel(const int* __restrict__ mask,
                                                        int* __restrict__ smallbuf) {
    const int py = blockIdx.x;   // 0..31 patch row
    const int b  = blockIdx.y;   // 0..15 image
    const int tid = threadIdx.x;
    const int lane = tid & 63, wv = tid >> 6;
    const int4* m4 = (const int4*)(mask + ((size_t)b << 18) + (size_t)py * 16 * 512);
    #pragma unroll
    for (int j = 0; j < 8; ++j) {
        int px  = wv + 4 * j;
        int row = lane >> 2, q = lane & 3;
        int4 v = m4[row * 128 + px * 4 + q];
        int mx = max(max(v.x, v.y), max(v.z, v.w));
        #pragma unroll
        for (int off = 32; off >= 1; off >>= 1) mx = max(mx, __shfl_xor(mx, off));
        if (lane == 0) smallbuf[((b << 5) + py) * 32 + px] = mx;
    }
}

// Kernel 2: MFMA separable-Gaussian SSIM over a 64x48 output tile.
// R13 revision. R12 FALSIFIED the occupancy theory: occupancy 44->78% with
// dur 62.5->79.9 us -- above ~3.5 waves/SIMD the kernel is work-throughput
// bound. The validated empirical law orders every measured config strictly
// by work-per-output (staged TSY32 61.0 < direct TSY32 62.3 < staged TSY16
// 69 < direct TSY16 79.9), insensitive to occupancy/pipelining. So: continue
// down that gradient. TSY 32->48 on the best-known body (R5: staged sA with
// COALESCED loads, packed-f16 P/S, row-major sHT + ds_read_b64_tr_b16
// transpose, single barrier): per output MFMA -6.5%, staging rows -8%,
// DS -5%, per-tile fixed costs /1.5. LDS 33 KB -> 4 blocks/CU (~50% occ,
// safely above the working 44%). Zero-pad rows 58..63 only meet zero taps
// (k'-m' >= 11) at valid outputs; groups b/c carry y<OUTD guards.
__global__ __launch_bounds__(256) void ssim_kernel(const float* __restrict__ img1,
                                                   const float* __restrict__ img2,
                                                   const int* __restrict__ smallbuf,
                                                   float* __restrict__ partial, GW gw) {
    __shared__ __align__(16) _Float16 sA[2][SROWS][SPITCH];  // 22528 B staged imgs
    __shared__ __align__(16) _Float16 sHT[4][SROWS][HT2P];   // 10240 B per-wave H-results
    __shared__ _Float16 gpad[48];               // zero-padded taps: gpad[15+i]=g[i]
    __shared__ int sdil[20];                    // 4 patch-rows x 5 patch-cols
    __shared__ float wsum[4];

    const int tid  = threadIdx.x;
    const int wv   = tid >> 6, lane = tid & 63;
    const int nidx = lane & 15, quad = lane >> 4;
    const int x0 = blockIdx.x * TSX, y0 = blockIdx.y * TSY;
    const int bc = blockIdx.z;               // b*3 + c
    const size_t base = (size_t)bc << 18;    // *512*512

    // Phase 0: stage both images, rows 0..57 from global (clamped addresses:
    // clamped data only ever reaches discarded outputs), rows 58..63 zeroed
    // (finite pad; zero-weighted taps at valid outputs).
    for (int i = tid; i < SROWS * 20; i += 256) {   // 1280 slots, 5/thread
        int r = i / 20, q = i - r * 20;
        if (r < 58) {
            int gy = y0 + r;     gy = gy > 511 ? 511 : gy;
            int gx = x0 + 4 * q; gx = gx > 508 ? 508 : gx;
            size_t off = base + ((size_t)gy << 9) + gx;
            f32x4 a = *(const f32x4*)(img1 + off);
            f32x4 b = *(const f32x4*)(img2 + off);
            *(f16x4*)&sA[0][r][4 * q] = __builtin_convertvector(a, f16x4);
            *(f16x4*)&sA[1][r][4 * q] = __builtin_convertvector(b, f16x4);
        } else {
            f16x4 z4 = {};
            *(f16x4*)&sA[0][r][4 * q] = z4;
            *(f16x4*)&sA[1][r][4 * q] = z4;
        }
    }

    // padded tap table (indices 15..25 hold g[0..10], rest zero)
    if (tid < 48) {
        int k = tid - 15;
        int kc = k < 0 ? 0 : (k > 10 ? 10 : k);      // clamp: no speculative OOB
        gpad[tid] = (k == kc) ? (_Float16)gw.g[kc] : (_Float16)0.f;
    }

    // fused 3x3 dilation lookup: tile spans patch rows 3*by .. 3*by+3 (window
    // reaches y0+57), patch cols bx*4 .. bx*4+4.
    if (tid >= 192 && tid < 212) {
        int t = tid - 192;
        int tr = t / 5, tc = t - tr * 5;
        int pr = 3 * (int)blockIdx.y + tr;
        int pc = (int)blockIdx.x * 4 + tc;
        int acc = 0;
        if (pr < 32 && pc < 32) {
            const int* sb = smallbuf + ((bc / 3) << 10);
            #pragma unroll
            for (int dy = -1; dy <= 1; ++dy)
                #pragma unroll
                for (int dx = -1; dx <= 1; ++dx) {
                    int ny = pr + dy, nx = pc + dx;
                    if (ny >= 0 && ny < 32 && nx >= 0 && nx < 32) acc |= sb[(ny << 5) + nx];
                }
        }
        sdil[t] = acc ? 1 : 0;
    }
    __syncthreads();

    // Toeplitz A-frag (shared by all passes): A[m=nidx][k=quad*8+j] = g[k-m].
    f16x8 af;
    {
        const _Float16* gp = &gpad[quad * 8 - nidx + 15];
        #pragma unroll
        for (int j = 0; j < 8; ++j) af[j] = gp[j];
    }

    // This wave handles output cols cb..cb+15 of the tile.
    const int cb = 16 * wv;

    // Raw a/b B-frags for 4 row-groups: lane = row 16h+nidx,
    // cols cb + quad*8 .. +7 (contiguous, 16B-aligned).
    f16x8 fa[4], fb[4];
    #pragma unroll
    for (int h = 0; h < 4; ++h) {
        fa[h] = *(const f16x8*)&sA[0][16 * h + nidx][cb + quad * 8];
        fb[h] = *(const f16x8*)&sA[1][16 * h + nidx][cb + quad * 8];
    }

    // Transpose-buffer addresses (per-wave region sHT[wv], 40 B rows):
    // write: lane(quad,nidx) holds (x' = 4*quad+r, y = 16h+nidx) -> word at
    //        row 16h+nidx, col 4*quad (one b64 per h; +320 f16 per h).
    _Float16* wp = &sHT[wv][nidx][quad * 4];
    // tr read: lane(q,m) fetches word (y = 8q + (m>>2) [+4 / +16v], w = m&3).
    lds_cf16* rp = (lds_cf16*)&sHT[wv][8 * quad + (nidx >> 2)][4 * (nidx & 3)];

    const f32x4 z = {0.f, 0.f, 0.f, 0.f};

    // Per map: 4 H-MFMAs -> row-major sHT -> 6 tr-reads -> 3 V-MFMAs.
    // (R5's verified in-order DS sequence, one more group.)
    f32x4 acc_a[4], acc_b[4], acc_c[4];
    #pragma unroll
    for (int mm = 0; mm < 4; ++mm) {
        #pragma unroll
        for (int h = 0; h < 4; ++h) {
            f16x8 f;
            if (mm == 0)      f = fa[h];
            else if (mm == 1) f = fb[h];
            else if (mm == 2) f = fa[h] * fb[h];
            else              f = fa[h] * fa[h] + fb[h] * fb[h];
            f32x4 c = mfma_f16(af, f, z);    // H-conv rows 16h..16h+15
            *(f16x4*)(wp + 320 * h) = __builtin_convertvector(c, f16x4);
        }
        // V-pass B-frags via HW transpose read. Group v uses k rows
        // 16v..16v+31 -> byte offsets 640v and 640v+160.
        f16x4 r0, r1, r2, r3, r4, r5;
        asm volatile("ds_read_b64_tr_b16 %0, %6 offset:0\n\t"
                     "ds_read_b64_tr_b16 %1, %6 offset:160\n\t"
                     "ds_read_b64_tr_b16 %2, %6 offset:640\n\t"
                     "ds_read_b64_tr_b16 %3, %6 offset:800\n\t"
                     "ds_read_b64_tr_b16 %4, %6 offset:1280\n\t"
                     "ds_read_b64_tr_b16 %5, %6 offset:1440"
                     : "=&v"(r0), "=&v"(r1), "=&v"(r2), "=&v"(r3),
                       "=&v"(r4), "=&v"(r5)
                     : "v"(rp) : "memory");
        asm volatile("s_waitcnt lgkmcnt(0)" ::: "memory");
        __builtin_amdgcn_sched_barrier(0);   // rule #18: keep MFMA after the wait
        f16x8 hba = __builtin_shufflevector(r0, r1, 0, 1, 2, 3, 4, 5, 6, 7);
        f16x8 hbb = __builtin_shufflevector(r2, r3, 0, 1, 2, 3, 4, 5, 6, 7);
        f16x8 hbc = __builtin_shufflevector(r4, r5, 0, 1, 2, 3, 4, 5, 6, 7);
        acc_a[mm] = mfma_f16(af, hba, z);
        acc_b[mm] = mfma_f16(af, hbb, z);
        acc_c[mm] = mfma_f16(af, hbc, z);
    }

    // Epilogue: lane holds 4 maps x 12 pixels: group a at y = y0+quad*4+r,
    // group b at +16, group c at +32; x = x0+cb+nidx. f32x2 packs (a,b);
    // group c scalar.
    const float C1v = 1e-4f, C2v = 9e-4f;  // L = 1 (inputs uniform [0,1))
    const float cm = gw.cm;
    float lsum = 0.f;
    {
        const int xl = cb + nidx;
        const int x = x0 + xl;
        if (x < OUTD) {
            const int lc0 = xl >> 4, lc1 = (xl + 10) >> 4;
            const int p0 = sdil[lc0]      & sdil[lc1];
            const int p1 = sdil[5 + lc0]  & sdil[5 + lc1];
            const int p2 = sdil[10 + lc0] & sdil[10 + lc1];
            const int p3 = sdil[15 + lc0] & sdil[15 + lc1];

            #pragma unroll
            for (int r = 0; r < 4; ++r) {
                int q4r = quad * 4 + r;
                int cond = q4r < 6;   // window stays within patch-row stripe
                int va = cond ? p0 : (p0 & p1);   // y = y0+q4r <= 495 < OUTD
                int yb = y0 + 16 + q4r;
                int vb = cond ? p1 : (p1 & p2);
                vb = (yb < OUTD) ? vb : 0;
                int yc = y0 + 32 + q4r;
                int vc = cond ? p2 : (p2 & p3);
                vc = (yc < OUTD) ? vc : 0;
                // groups a,b packed
                f32x2 mu1 = {acc_a[0][r], acc_b[0][r]};
                f32x2 mu2 = {acc_a[1][r], acc_b[1][r]};
                f32x2 Sab = {acc_a[2][r], acc_b[2][r]};
                f32x2 Sss = {acc_a[3][r], acc_b[3][r]};
                mu1 *= cm; mu2 *= cm; Sab *= cm; Sss *= cm;
                f32x2 mu1s = mu1 * mu1, mu2s = mu2 * mu2, mu12 = mu1 * mu2;
                f32x2 sg12 = Sab - mu12;
                f32x2 sigS = Sss - mu1s - mu2s;
                f32x2 num = (2.f * mu12 + C1v) * (2.f * sg12 + C2v);
                f32x2 den = (mu1s + mu2s + C1v) * (sigS + C2v);
                if (va) lsum += __fdividef(num[0], den[0]);
                if (vb) lsum += __fdividef(num[1], den[1]);
                // group c scalar
                float m1 = acc_c[0][r] * cm, m2 = acc_c[1][r] * cm;
                float Pb = acc_c[2][r] * cm, Ss = acc_c[3][r] * cm;
                float m1s = m1 * m1, m2s = m2 * m2, m12 = m1 * m2;
                float s12 = Pb - m12;
                float sS  = Ss - m1s - m2s;
                float nc = (2.f * m12 + C1v) * (2.f * s12 + C2v);
                float dc = (m1s + m2s + C1v) * (sS + C2v);
                if (vc) lsum += __fdividef(nc, dc);
            }
        }
    }

    // block reduction -> one float partial per block (deterministic, no atomics)
    #pragma unroll
    for (int off = 32; off >= 1; off >>= 1) lsum += __shfl_xor(lsum, off);
    if ((tid & 63) == 0) wsum[tid >> 6] = lsum;
    __syncthreads();
    if (tid == 0)
        partial[((int)blockIdx.z * GY + (int)blockIdx.y) * GX + (int)blockIdx.x] =
            wsum[0] + wsum[1] + wsum[2] + wsum[3];
}

// Kernel 3: reduce partials, divide by element count (deterministic order)
__global__ __launch_bounds__(256) void finalize_kernel(const float* __restrict__ partial,
                                                       float* __restrict__ out) {
    __shared__ double sd[256];
    double s = 0.0;
    const f32x4* p4 = (const f32x4*)partial;
    for (int i = threadIdx.x; i < NPARTIAL / 4; i += 256) {
        f32x4 vv = p4[i];
        s += (double)vv.x + (double)vv.y + (double)vv.z + (double)vv.w;
    }
    sd[threadIdx.x] = s;
    __syncthreads();
    for (int st = 128; st >= 1; st >>= 1) {
        if (threadIdx.x < st) sd[threadIdx.x] += sd[threadIdx.x + st];
        __syncthreads();
    }
    if (threadIdx.x == 0) out[0] = (float)(sd[0] / 12096192.0);  // 16*3*502*502
}

// Round a positive normal double to the nearest fp16-representable float (RTNE).
static inline float fp16_rtne(double x) {
    float f = (float)x;
    uint32_t u; memcpy(&u, &f, 4);
    // drop 13 mantissa bits (23 -> 10), RTNE with carry into exponent
    u = (u + 0xFFFu + ((u >> 13) & 1u)) & ~0x1FFFu;
    memcpy(&f, &u, 4);
    return f;
}

extern "C" void kernel_launch(void* const* d_in, const int* in_sizes, int n_in,
                              void* d_out, int out_size, void* d_ws, size_t ws_size,
                              hipStream_t stream) {
    const float* img1 = (const float*)d_in[0];
    const float* img2 = (const float*)d_in[1];
    const int*   mask = (const int*)d_in[2];
    float* out = (float*)d_out;

    char* ws = (char*)d_ws;
    float* partial  = (float*)ws;                        // 4224 floats
    int*   smallbuf = (int*)(ws + NPARTIAL * 4);         // 16*32*32 ints

    // Gaussian(sigma=1.5), normalized in double, then each tap rounded to
    // fp16 (RTNE). cm = 1/(sum of rounded taps)^2 removes the systematic
    // scale error of fp16 conv weights (applied to all 4 maps in epilogue).
    GW gw;
    double gd[NTAP], gsum = 0.0;
    for (int i = 0; i < NTAP; ++i) {
        double x = (double)(i - 5);
        gd[i] = exp(-(x * x) / 4.5);
        gsum += gd[i];
    }
    double wsumr = 0.0;
    for (int i = 0; i < NTAP; ++i) {
        gw.g[i] = fp16_rtne(gd[i] / gsum);
        wsumr += (double)gw.g[i];
    }
    gw.cm = (float)(1.0 / (wsumr * wsumr));

    patch_max_kernel<<<dim3(32, 16), 256, 0, stream>>>(mask, smallbuf);
    ssim_kernel<<<dim3(GX, GY, 48), 256, 0, stream>>>(img1, img2, smallbuf, partial, gw);
    finalize_kernel<<<1, 256, 0, stream>>>(partial, out);
}